// Round 1
// baseline (1114.083 us; speedup 1.0000x reference)
//
#include <hip/hip_runtime.h>

// Problem constants
// x1: (4,128,128,128) f32   [b][c][i][j]
// x2_feat: (131072, 64) f32 -> overwrites batches 0,1 of merged
// w_up: (128,64,2,2), b_up: (64)
// w1,w2: (64,64,3,3), b1,b2: (64), a1,a2: (1)
// merged/h/out: (4,64,256,256) f32

#define HC 128   // coarse H
#define WC 128   // coarse W
#define HF 256   // fine H
#define WF 256   // fine W

// ---------------------------------------------------------------------------
// Kernel 1: copy x2_feat (row-major [pos][ch]) into merged NCHW for b=0,1.
// Tile: 64 consecutive positions x 64 channels, transposed through LDS.
// ---------------------------------------------------------------------------
__global__ __launch_bounds__(256) void k_copy_x2(const float* __restrict__ x2,
                                                 float* __restrict__ merged) {
    __shared__ float lds[64][68];   // [pos][ch], pad to 68 floats (16B-aligned rows)
    const int t  = threadIdx.x;
    const int b  = blockIdx.x >> 10;          // 1024 tiles per batch image
    const int s0 = (blockIdx.x & 1023) * 64;  // linear spatial start (one row segment)

    // load: 1024 float4 (64 pos x 16 float4-of-ch)
    const float4* src = (const float4*)(x2 + (size_t)(b * 65536 + s0) * 64);
#pragma unroll
    for (int r = 0; r < 4; ++r) {
        int idx = r * 256 + t;        // 0..1023
        int p = idx >> 4, c4 = idx & 15;
        float4 v = src[p * 16 + c4];
        *(float4*)&lds[p][c4 * 4] = v;
    }
    __syncthreads();

    // write: for each channel c, a contiguous 64-wide x-run
    const int y  = s0 >> 8;
    const int x0 = s0 & 255;
#pragma unroll
    for (int r = 0; r < 4; ++r) {
        int idx = r * 256 + t;
        int c = idx >> 4, p4 = idx & 15;
        float4 v = make_float4(lds[p4 * 4 + 0][c], lds[p4 * 4 + 1][c],
                               lds[p4 * 4 + 2][c], lds[p4 * 4 + 3][c]);
        float* dst = merged + ((size_t)(b * 64 + c) << 16) + s0 + p4 * 4;
        *(float4*)dst = v;
        (void)y; (void)x0;
    }
}

// ---------------------------------------------------------------------------
// Kernel 2: ConvTranspose2d k=2 s=2 for b=2,3 only.
// Block: coarse tile 8(i) x 32(j), 16 output channels, all 128 cin.
// ---------------------------------------------------------------------------
__global__ __launch_bounds__(256) void k_upsample(const float* __restrict__ x1,
                                                  const float* __restrict__ wup,
                                                  const float* __restrict__ bup,
                                                  float* __restrict__ merged) {
    __shared__ float lx[16][256];   // [cin_chunk][i*32+j]
    const int t  = threadIdx.x;
    const int i  = t >> 5, j = t & 31;
    const int tj = blockIdx.x & 3,  ti = blockIdx.x >> 2;
    const int j0 = tj * 32, i0 = ti * 8;
    const int o0 = blockIdx.y * 16;
    const int bb = 2 + blockIdx.z;

    float acc[16][4];
#pragma unroll
    for (int o = 0; o < 16; ++o)
#pragma unroll
        for (int k = 0; k < 4; ++k) acc[o][k] = 0.f;

    for (int c0 = 0; c0 < 128; c0 += 16) {
        __syncthreads();
#pragma unroll
        for (int r = 0; r < 16; ++r) {
            int idx = r * 256 + t;
            int c = idx >> 8, pos = idx & 255;
            int ii = pos >> 5, jj = pos & 31;
            lx[c][pos] = x1[(((size_t)bb * 128 + c0 + c) * 128 + (i0 + ii)) * 128 + (j0 + jj)];
        }
        __syncthreads();
        for (int c = 0; c < 16; ++c) {
            float xv = lx[c][t];
            const float* wp = wup + ((size_t)(c0 + c) * 64 + o0) * 4;  // block-uniform -> s_load
#pragma unroll
            for (int o = 0; o < 16; ++o) {
                acc[o][0] += xv * wp[o * 4 + 0];
                acc[o][1] += xv * wp[o * 4 + 1];
                acc[o][2] += xv * wp[o * 4 + 2];
                acc[o][3] += xv * wp[o * 4 + 3];
            }
        }
    }

    const int yg = 2 * (i0 + i);
    const int xg = 2 * (j0 + j);
#pragma unroll
    for (int o = 0; o < 16; ++o) {
        float bv = bup[o0 + o];
        float* dst = merged + (((size_t)bb * 64 + o0 + o) * HF + yg) * WF + xg;
        float2 v0 = {acc[o][0] + bv, acc[o][1] + bv};  // p=0: (q=0,q=1)
        float2 v1 = {acc[o][2] + bv, acc[o][3] + bv};  // p=1
        *(float2*)dst = v0;
        *(float2*)(dst + WF) = v1;
    }
}

// ---------------------------------------------------------------------------
// Kernel 3: 3x3 SAME conv (64->64) + bias + PReLU, direct f32 with LDS tiling.
// Block: 32(x) x 8(y) spatial tile, 16 output channels; threads = (x:32, oo:8),
// each thread computes 8 rows x 2 couts.
// ---------------------------------------------------------------------------
__global__ __launch_bounds__(256) void k_conv3(const float* __restrict__ in,
                                               const float* __restrict__ w,
                                               const float* __restrict__ bias,
                                               const float* __restrict__ alpha,
                                               float* __restrict__ out) {
    __shared__ float lds_in[8][10][34];   // [cin][row(10=8+2)][col(34=32+2)]
    __shared__ float lds_w[16][8][9];     // [o][cin][tap]

    const int t  = threadIdx.x;
    const int x  = t & 31;
    const int oo = t >> 5;                 // 0..7
    const int tx = blockIdx.x & 7, ty = blockIdx.x >> 3;
    const int x0 = tx * 32, y0 = ty * 8;
    const int o0 = blockIdx.y * 16;
    const int bb = blockIdx.z;

    float accA[8], accB[8];
#pragma unroll
    for (int yy = 0; yy < 8; ++yy) { accA[yy] = 0.f; accB[yy] = 0.f; }

    for (int c0 = 0; c0 < 64; c0 += 8) {
        __syncthreads();
        // stage input tile with halo (zero pad at image edges)
        for (int idx = t; idx < 8 * 10 * 34; idx += 256) {
            int c = idx / 340;
            int rem = idx - c * 340;
            int r = rem / 34;
            int xx = rem - r * 34;
            int gy = y0 + r - 1;
            int gx = x0 + xx - 1;
            float v = 0.f;
            if (gy >= 0 && gy < HF && gx >= 0 && gx < WF)
                v = in[(((size_t)bb * 64 + c0 + c) * HF + gy) * WF + gx];
            lds_in[c][r][xx] = v;
        }
        // stage weights
        for (int idx = t; idx < 16 * 8 * 9; idx += 256) {
            int o = idx / 72;
            int rem = idx - o * 72;
            int c = rem / 9;
            int k = rem - c * 9;
            lds_w[o][c][k] = w[((size_t)(o0 + o) * 64 + c0 + c) * 9 + k];
        }
        __syncthreads();

#pragma unroll
        for (int c = 0; c < 8; ++c) {
            float wA[9], wB[9];
#pragma unroll
            for (int k = 0; k < 9; ++k) {
                wA[k] = lds_w[oo][c][k];
                wB[k] = lds_w[oo + 8][c][k];
            }
#pragma unroll
            for (int r = 0; r < 10; ++r) {
                float a0 = lds_in[c][r][x];
                float a1 = lds_in[c][r][x + 1];
                float a2 = lds_in[c][r][x + 2];
#pragma unroll
                for (int ky = 0; ky < 3; ++ky) {
                    int yy = r - ky;   // output row this LDS row contributes to
                    if (yy >= 0 && yy < 8) {
                        accA[yy] += a0 * wA[ky * 3 + 0] + a1 * wA[ky * 3 + 1] + a2 * wA[ky * 3 + 2];
                        accB[yy] += a0 * wB[ky * 3 + 0] + a1 * wB[ky * 3 + 1] + a2 * wB[ky * 3 + 2];
                    }
                }
            }
        }
    }

    const float al = alpha[0];
    const float bA = bias[o0 + oo];
    const float bB = bias[o0 + oo + 8];
#pragma unroll
    for (int yy = 0; yy < 8; ++yy) {
        float vA = accA[yy] + bA;
        vA = vA >= 0.f ? vA : al * vA;
        out[(((size_t)bb * 64 + o0 + oo) * HF + y0 + yy) * WF + x0 + x] = vA;
        float vB = accB[yy] + bB;
        vB = vB >= 0.f ? vB : al * vB;
        out[(((size_t)bb * 64 + o0 + oo + 8) * HF + y0 + yy) * WF + x0 + x] = vB;
    }
}

// ---------------------------------------------------------------------------
extern "C" void kernel_launch(void* const* d_in, const int* in_sizes, int n_in,
                              void* d_out, int out_size, void* d_ws, size_t ws_size,
                              hipStream_t stream) {
    const float* x1  = (const float*)d_in[0];
    const float* x2  = (const float*)d_in[1];
    const float* wup = (const float*)d_in[2];
    const float* bup = (const float*)d_in[3];
    const float* w1  = (const float*)d_in[4];
    const float* b1  = (const float*)d_in[5];
    const float* a1  = (const float*)d_in[6];
    const float* w2  = (const float*)d_in[7];
    const float* b2  = (const float*)d_in[8];
    const float* a2  = (const float*)d_in[9];

    float* out    = (float*)d_out;
    float* merged = out;             // reuse d_out as scratch for merged
    float* h      = (float*)d_ws;    // needs 4*64*256*256*4 = 64 MiB

    // Stage 1: build merged (4,64,256,256) in d_out
    k_copy_x2<<<2048, 256, 0, stream>>>(x2, merged);
    k_upsample<<<dim3(64, 4, 2), 256, 0, stream>>>(x1, wup, bup, merged);
    // Stage 2: h = PReLU(conv3x3(merged, w1) + b1)   (d_out -> d_ws)
    k_conv3<<<dim3(256, 4, 4), 256, 0, stream>>>(merged, w1, b1, a1, h);
    // Stage 3: out = PReLU(conv3x3(h, w2) + b2)      (d_ws -> d_out)
    k_conv3<<<dim3(256, 4, 4), 256, 0, stream>>>(h, w2, b2, a2, out);
}

// Round 2
// 163.155 us; speedup vs baseline: 6.8284x; 6.8284x over previous
//
#include <hip/hip_runtime.h>

typedef __attribute__((ext_vector_type(8))) short short8;
typedef __attribute__((ext_vector_type(4))) float f32x4;

#define HF 256
#define WF 256

__device__ __forceinline__ ushort f2bf(float f) {
    uint u = __builtin_bit_cast(uint, f);
    u = (u + 0x7FFFu + ((u >> 16) & 1u)) >> 16;
    return (ushort)u;
}
__device__ __forceinline__ uint pack2(float a, float b) {
    return (uint)f2bf(a) | ((uint)f2bf(b) << 16);
}
__device__ __forceinline__ float prelu(float v, float al) { return v >= 0.f ? v : al * v; }

// ---------------------------------------------------------------------------
// Weight prep: w[o][c][3][3] f32  ->  wT[tap][o][c] bf16 (c contiguous)
// ---------------------------------------------------------------------------
__global__ __launch_bounds__(256) void k_wprep(const float* __restrict__ w1,
                                               const float* __restrict__ w2,
                                               ushort* __restrict__ wT1,
                                               ushort* __restrict__ wT2) {
    int idx = blockIdx.x * 256 + threadIdx.x;   // [tap][o][c] : 9*64*64 = 36864
    int tap = idx >> 12;
    int oc  = idx & 4095;                        // o*64 + c
    int src = oc * 9 + tap;
    wT1[idx] = f2bf(w1[src]);
    wT2[idx] = f2bf(w2[src]);
}

// ---------------------------------------------------------------------------
// ConvTranspose2d k=2 s=2 for b=2,3 -> upB bf16 NHWC [z][y][x][64]
// ---------------------------------------------------------------------------
__global__ __launch_bounds__(256) void k_upsample(const float* __restrict__ x1,
                                                  const float* __restrict__ wup,
                                                  const float* __restrict__ bup,
                                                  ushort* __restrict__ upB) {
    __shared__ float lx[16][256];
    const int t = threadIdx.x;
    const int i = t >> 5, j = t & 31;
    const int tj = blockIdx.x & 3, ti = blockIdx.x >> 2;
    const int j0 = tj * 32, i0 = ti * 8;
    const int o0 = blockIdx.y * 16;
    const int z  = blockIdx.z;        // 0,1 -> global batch 2,3
    const int gb = 2 + z;

    float acc[16][4];
#pragma unroll
    for (int o = 0; o < 16; ++o)
#pragma unroll
        for (int k = 0; k < 4; ++k) acc[o][k] = 0.f;

    for (int c0 = 0; c0 < 128; c0 += 16) {
        __syncthreads();
#pragma unroll
        for (int r = 0; r < 16; ++r) {
            int idx = r * 256 + t;
            int c = idx >> 8, pos = idx & 255;
            int ii = pos >> 5, jj = pos & 31;
            lx[c][pos] = x1[(((size_t)gb * 128 + c0 + c) * 128 + (i0 + ii)) * 128 + (j0 + jj)];
        }
        __syncthreads();
        for (int c = 0; c < 16; ++c) {
            float xv = lx[c][t];
            const float* wp = wup + ((size_t)(c0 + c) * 64 + o0) * 4;  // block-uniform
#pragma unroll
            for (int o = 0; o < 16; ++o) {
                acc[o][0] += xv * wp[o * 4 + 0];
                acc[o][1] += xv * wp[o * 4 + 1];
                acc[o][2] += xv * wp[o * 4 + 2];
                acc[o][3] += xv * wp[o * 4 + 3];
            }
        }
    }

    float bv[16];
#pragma unroll
    for (int o = 0; o < 16; ++o) bv[o] = bup[o0 + o];
    const int yg = 2 * (i0 + i), xg = 2 * (j0 + j);
#pragma unroll
    for (int k = 0; k < 4; ++k) {          // k = p*2 + q
        uint pk[8];
#pragma unroll
        for (int o2 = 0; o2 < 8; ++o2)
            pk[o2] = pack2(acc[2 * o2][k] + bv[2 * o2], acc[2 * o2 + 1][k] + bv[2 * o2 + 1]);
        ushort* dst = upB + ((size_t)((z * HF + yg + (k >> 1)) * WF + xg + (k & 1))) * 64 + o0;
        *(uint4*)dst       = make_uint4(pk[0], pk[1], pk[2], pk[3]);
        *((uint4*)dst + 1) = make_uint4(pk[4], pk[5], pk[6], pk[7]);
    }
}

// ---------------------------------------------------------------------------
// 3x3 SAME conv 64->64 + bias + PReLU via bf16 MFMA (shifted-tap implicit GEMM).
// Block: 32(x) x 4(y) spatial, all 64 couts, 4 waves (wave = one y-row).
// IN_MODE 0: b<2 from x2 (f32 NHWC), b>=2 from upB (bf16 NHWC); 1: inB bf16 NHWC.
// OUT_NHWC 1: write bf16 NHWC (outB); 0: write f32 NCHW (outF).
// ---------------------------------------------------------------------------
template<int IN_MODE, int OUT_NHWC>
__global__ __launch_bounds__(256) void k_conv(const float* __restrict__ x2,
                                              const ushort* __restrict__ upB,
                                              const ushort* __restrict__ inB,
                                              const ushort* __restrict__ wT,
                                              const float* __restrict__ bias,
                                              const float* __restrict__ alpha,
                                              ushort* __restrict__ outB,
                                              float* __restrict__ outF) {
    __shared__ __align__(16) ushort inL[6 * 34 * 64];   // [r][x][c], XOR-swizzled on x
    __shared__ __align__(16) ushort wL[2][64 * 64];     // [o][c],    XOR-swizzled on o
    __shared__ float biasL[64];

    const int t   = threadIdx.x;
    const int w   = t >> 6;          // wave id = output row within tile
    const int l   = t & 63;
    const int l15 = l & 15;
    const int l4  = l >> 4;
    const int x0  = (blockIdx.x & 7) * 32;
    const int y0  = (blockIdx.x >> 3) * 4;
    const int b   = blockIdx.y;

    // ---- stage input tile (6 x 34 x 64ch), zero-padded halo
    for (int q = t; q < 6 * 34 * 8; q += 256) {
        int r   = q / 272;
        int rem = q - r * 272;
        int x   = rem >> 3;
        int c8  = rem & 7;
        int gy = y0 - 1 + r;
        int gx = x0 - 1 + x;
        uint4 v = make_uint4(0u, 0u, 0u, 0u);
        if ((unsigned)gy < HF && (unsigned)gx < WF) {
            size_t pos = (size_t)(b * HF + gy) * WF + gx;
            if (IN_MODE == 1) {
                v = *(const uint4*)(inB + pos * 64 + c8 * 8);
            } else if (b < 2) {
                const float4* s = (const float4*)(x2 + pos * 64 + c8 * 8);
                float4 u0 = s[0], u1 = s[1];
                v = make_uint4(pack2(u0.x, u0.y), pack2(u0.z, u0.w),
                               pack2(u1.x, u1.y), pack2(u1.z, u1.w));
            } else {
                size_t p2 = (size_t)((b - 2) * HF + gy) * WF + gx;
                v = *(const uint4*)(upB + p2 * 64 + c8 * 8);
            }
        }
        int ad = (q * 16) ^ ((x & 7) << 4);
        *(uint4*)((char*)inL + ad) = v;
    }
    // ---- stage weights tap 0
    {
        const uint4* src = (const uint4*)wT;
        for (int q = t; q < 512; q += 256) {
            int o  = q >> 3;
            int ad = (q * 16) ^ ((o & 7) << 4);
            *(uint4*)((char*)wL[0] + ad) = src[q];
        }
    }
    if (t < 64) biasL[t] = bias[t];
    __syncthreads();

    f32x4 acc[8];
#pragma unroll
    for (int a = 0; a < 8; ++a) acc[a] = (f32x4){0.f, 0.f, 0.f, 0.f};

#pragma unroll
    for (int tap = 0; tap < 9; ++tap) {
        if (tap < 8) {   // prefetch next tap's weights into other buffer
            const uint4* src = (const uint4*)(wT + (tap + 1) * 4096);
            ushort* dstw = wL[(tap + 1) & 1];
            for (int q = t; q < 512; q += 256) {
                int o  = q >> 3;
                int ad = (q * 16) ^ ((o & 7) << 4);
                *(uint4*)((char*)dstw + ad) = src[q];
            }
        }
        const int ky = tap / 3, kx = tap % 3;
        const char* wCur = (const char*)wL[tap & 1];
#pragma unroll
        for (int ks = 0; ks < 2; ++ks) {
            const int cb2 = ks * 64 + (l4 << 4);   // byte offset of lane's 8-ch chunk
            short8 ifr[2], wfr[4];
#pragma unroll
            for (int nf = 0; nf < 2; ++nf) {
                int xl = nf * 16 + l15 + kx;
                int ad = (((w + ky) * 34 + xl) * 128 + cb2) ^ ((xl & 7) << 4);
                ifr[nf] = *(const short8*)((const char*)inL + ad);
            }
#pragma unroll
            for (int wf = 0; wf < 4; ++wf) {
                int o  = wf * 16 + l15;
                int ad = (o * 128 + cb2) ^ ((o & 7) << 4);
                wfr[wf] = *(const short8*)(wCur + ad);
            }
#pragma unroll
            for (int wf = 0; wf < 4; ++wf)
#pragma unroll
                for (int nf = 0; nf < 2; ++nf) {
                    if (OUT_NHWC)
                        acc[wf * 2 + nf] = __builtin_amdgcn_mfma_f32_16x16x32_bf16(
                            wfr[wf], ifr[nf], acc[wf * 2 + nf], 0, 0, 0);   // D = W*X
                    else
                        acc[wf * 2 + nf] = __builtin_amdgcn_mfma_f32_16x16x32_bf16(
                            ifr[nf], wfr[wf], acc[wf * 2 + nf], 0, 0, 0);   // D = X*W
                }
        }
        if (tap < 8) __syncthreads();
    }

    const float al = alpha[0];
    const int y = y0 + w;
    if (OUT_NHWC) {
        // D rows = cout ((l>>4)*4+j), cols = x (l&15): 4 consecutive couts per lane
#pragma unroll
        for (int wf = 0; wf < 4; ++wf)
#pragma unroll
            for (int nf = 0; nf < 2; ++nf) {
                f32x4 v = acc[wf * 2 + nf];
                int cb = wf * 16 + (l4 << 2);
                uint lo = pack2(prelu(v.x + biasL[cb + 0], al), prelu(v.y + biasL[cb + 1], al));
                uint hi = pack2(prelu(v.z + biasL[cb + 2], al), prelu(v.w + biasL[cb + 3], al));
                int x = x0 + nf * 16 + l15;
                *(uint2*)(outB + ((size_t)(b * HF + y) * WF + x) * 64 + cb) = make_uint2(lo, hi);
            }
    } else {
        // D rows = x ((l>>4)*4+j), cols = cout (l&15): float4 along x in NCHW
#pragma unroll
        for (int wf = 0; wf < 4; ++wf)
#pragma unroll
            for (int mf = 0; mf < 2; ++mf) {
                f32x4 v = acc[wf * 2 + mf];
                int cout = wf * 16 + l15;
                int xb   = x0 + mf * 16 + (l4 << 2);
                float bb = biasL[cout];
                float4 st;
                st.x = prelu(v.x + bb, al);
                st.y = prelu(v.y + bb, al);
                st.z = prelu(v.z + bb, al);
                st.w = prelu(v.w + bb, al);
                *(float4*)(outF + (((size_t)b * 64 + cout) << 16) + y * WF + xb) = st;
            }
    }
}

// ---------------------------------------------------------------------------
extern "C" void kernel_launch(void* const* d_in, const int* in_sizes, int n_in,
                              void* d_out, int out_size, void* d_ws, size_t ws_size,
                              hipStream_t stream) {
    const float* x1  = (const float*)d_in[0];
    const float* x2  = (const float*)d_in[1];
    const float* wup = (const float*)d_in[2];
    const float* bup = (const float*)d_in[3];
    const float* w1  = (const float*)d_in[4];
    const float* b1  = (const float*)d_in[5];
    const float* a1  = (const float*)d_in[6];
    const float* w2  = (const float*)d_in[7];
    const float* b2  = (const float*)d_in[8];
    const float* a2  = (const float*)d_in[9];

    char* ws = (char*)d_ws;
    ushort* upB = (ushort*)ws;                           // 16 MiB (b=2,3 NHWC bf16)
    ushort* hB  = (ushort*)(ws + (size_t)(16 << 20));    // 32 MiB (NHWC bf16)
    ushort* wT1 = (ushort*)(ws + (size_t)(48 << 20));    // 72 KiB
    ushort* wT2 = wT1 + 9 * 64 * 64;                     // 72 KiB
    float* out = (float*)d_out;

    k_wprep<<<144, 256, 0, stream>>>(w1, w2, wT1, wT2);
    k_upsample<<<dim3(64, 4, 2), 256, 0, stream>>>(x1, wup, bup, upB);
    k_conv<0, 1><<<dim3(512, 4), 256, 0, stream>>>(x2, upB, nullptr, wT1, b1, a1, hB, nullptr);
    k_conv<1, 0><<<dim3(512, 4), 256, 0, stream>>>(nullptr, nullptr, hB, wT2, b2, a2, nullptr, out);
}

// Round 4
// 104.449 us; speedup vs baseline: 10.6663x; 1.5621x over previous
//
#include <hip/hip_runtime.h>

typedef __attribute__((ext_vector_type(8))) short short8;
typedef __attribute__((ext_vector_type(4))) float f32x4;

#define HF 256
#define WF 256

__device__ __forceinline__ ushort f2bf(float f) {
    uint u = __builtin_bit_cast(uint, f);
    u = (u + 0x7FFFu + ((u >> 16) & 1u)) >> 16;
    return (ushort)u;
}
__device__ __forceinline__ uint pack2(float a, float b) {
    return (uint)f2bf(a) | ((uint)f2bf(b) << 16);
}
__device__ __forceinline__ float prelu(float v, float al) { return v >= 0.f ? v : al * v; }

// ---------------------------------------------------------------------------
// Weight prep A: w[o][c][3][3] f32 -> wT[tap][o][c] bf16 (for the two convs)
// ---------------------------------------------------------------------------
__global__ __launch_bounds__(256) void k_wprep(const float* __restrict__ w1,
                                               const float* __restrict__ w2,
                                               ushort* __restrict__ wT1,
                                               ushort* __restrict__ wT2) {
    int idx = blockIdx.x * 256 + threadIdx.x;   // [tap][o][c] : 9*64*64 = 36864
    int tap = idx >> 12;
    int oc  = idx & 4095;
    int src = oc * 9 + tap;
    wT1[idx] = f2bf(w1[src]);
    wT2[idx] = f2bf(w2[src]);
}

// ---------------------------------------------------------------------------
// Weight prep B: wup[c][o][p][q] f32 -> wupT[out = (p*2+q)*64 + o][c] bf16
// ---------------------------------------------------------------------------
__global__ __launch_bounds__(256) void k_wprep_up(const float* __restrict__ wup,
                                                  ushort* __restrict__ wupT) {
    int idx = blockIdx.x * 256 + threadIdx.x;   // 256*128 = 32768
    int out = idx >> 7;
    int c   = idx & 127;
    int k   = out >> 6;       // p*2+q
    int o   = out & 63;
    wupT[idx] = f2bf(wup[c * 256 + o * 4 + k]);
}

// ---------------------------------------------------------------------------
// ConvTranspose2d k=2 s=2 for b=2,3 via bf16 MFMA -> upB NHWC [z][y][x][64]
// Block: 512 threads (8 waves), tile = 64 coarse j of one row i, all 256 outs.
// Wave (pg, oh): pg = 16-pos group, oh = 128-out half. LDS: A 16K + B 64K,
// output restaged in first 32K after compute.
// ---------------------------------------------------------------------------
__global__ __launch_bounds__(512) void k_upsample_mfma(const float* __restrict__ x1,
                                                       const ushort* __restrict__ wupT,
                                                       const float* __restrict__ bup,
                                                       ushort* __restrict__ upB) {
    __shared__ __align__(16) char lds[81920];   // [0,16K): A [64 j][128 c] swz
                                                // [16K,80K): B [256 out][128 c] swz
                                                // after compute: [0,32K) OUT [2 p][128 x][64 o]

    const int t   = threadIdx.x;
    const int l   = t & 63;
    const int l15 = l & 15;
    const int l4  = l >> 4;
    const int w   = t >> 6;
    const int pg  = w & 3;        // pos group (16 j)
    const int oh  = w >> 2;       // out half (128 outs)
    const int i   = blockIdx.x >> 1;
    const int j0  = (blockIdx.x & 1) * 64;
    const int z   = blockIdx.y;
    const int gb  = 2 + z;

    // ---- stage A: x1[gb][c][i][j0..j0+64) f32 -> bf16 [j][c] swizzled
    {
        const int j  = t & 63;
        const int cg = t >> 6;                     // 8 c-groups of 16
        const size_t base = ((size_t)gb * 128) * 16384 + (size_t)i * 128 + j0 + j;
        float xv[16];
#pragma unroll
        for (int r = 0; r < 2; ++r)
#pragma unroll
            for (int cc = 0; cc < 8; ++cc)
                xv[r * 8 + cc] = x1[base + (size_t)(cg * 16 + r * 8 + cc) * 16384];
#pragma unroll
        for (int r = 0; r < 2; ++r) {
            short8 pk;
#pragma unroll
            for (int cc = 0; cc < 8; ++cc) pk[cc] = (short)f2bf(xv[r * 8 + cc]);
            int ad = (j * 256 + (cg * 16 + r * 8) * 2) ^ ((j & 15) << 4);
            *(short8*)(lds + ad) = pk;
        }
    }
    // ---- stage B: wupT [256 out][128 c] bf16, swizzled (16 uint4 per row!)
    {
        const uint4* src = (const uint4*)wupT;
#pragma unroll
        for (int rep = 0; rep < 8; ++rep) {
            int q   = rep * 512 + t;               // 4096 uint4
            int out = q >> 4, c16 = q & 15;        // 128 c = 16 uint4 per out row
            int ad  = 16384 + ((out * 256 + c16 * 16) ^ ((out & 15) << 4));
            *(uint4*)(lds + ad) = src[q];
        }
    }
    float bvv[4];
#pragma unroll
    for (int ob = 0; ob < 4; ++ob) bvv[ob] = bup[ob * 16 + l15];
    __syncthreads();

    // ---- compute: D[pos][out] = sum_c A[pos][c] * B[out][c]
    f32x4 acc[2][4];
#pragma unroll
    for (int kk = 0; kk < 2; ++kk)
#pragma unroll
        for (int ob = 0; ob < 4; ++ob) acc[kk][ob] = (f32x4){0.f, 0.f, 0.f, 0.f};

#pragma unroll
    for (int ks = 0; ks < 4; ++ks) {
        const int cb = ks * 64 + (l4 << 4);
        const int rowA = pg * 16 + l15;
        short8 xfr = *(const short8*)(lds + ((rowA * 256 + cb) ^ ((rowA & 15) << 4)));
#pragma unroll
        for (int kk = 0; kk < 2; ++kk)
#pragma unroll
            for (int ob = 0; ob < 4; ++ob) {
                int out = (oh * 2 + kk) * 64 + ob * 16 + l15;
                short8 wfr = *(const short8*)(lds + 16384 +
                              ((out * 256 + cb) ^ ((out & 15) << 4)));
                acc[kk][ob] = __builtin_amdgcn_mfma_f32_16x16x32_bf16(xfr, wfr, acc[kk][ob], 0, 0, 0);
            }
    }
    __syncthreads();

    // ---- restage output tile [2 p][128 x][64 o] bf16 into LDS [0,32K)
    ushort* OUT = (ushort*)lds;
#pragma unroll
    for (int kk = 0; kk < 2; ++kk) {
        const int k = oh * 2 + kk, p = k >> 1, q = k & 1;
#pragma unroll
        for (int ob = 0; ob < 4; ++ob) {
            const int o = ob * 16 + l15;
#pragma unroll
            for (int r = 0; r < 4; ++r) {
                int jl = pg * 16 + l4 * 4 + r;
                int x  = 2 * jl + q;
                OUT[(p * 128 + x) * 64 + o] = f2bf(acc[kk][ob][r] + bvv[ob]);
            }
        }
    }
    __syncthreads();

    // ---- coalesced store: per p, a contiguous 16 KB run in upB
#pragma unroll
    for (int rep = 0; rep < 4; ++rep) {
        int idx = rep * 512 + t;                  // 2048 uint4
        int p   = idx >> 10;
        int y   = 2 * i + p;
        uint4 v = *(const uint4*)(lds + idx * 16);
        size_t g = (size_t)(z * HF + y) * 2048 + (size_t)j0 * 16 + (idx & 1023);
        ((uint4*)upB)[g] = v;
    }
}

// ---------------------------------------------------------------------------
// 3x3 SAME conv 64->64 + bias + PReLU via bf16 MFMA (shifted-tap implicit GEMM).
// ---------------------------------------------------------------------------
template<int IN_MODE, int OUT_NHWC>
__global__ __launch_bounds__(256) void k_conv(const float* __restrict__ x2,
                                              const ushort* __restrict__ upB,
                                              const ushort* __restrict__ inB,
                                              const ushort* __restrict__ wT,
                                              const float* __restrict__ bias,
                                              const float* __restrict__ alpha,
                                              ushort* __restrict__ outB,
                                              float* __restrict__ outF) {
    __shared__ __align__(16) ushort inL[6 * 34 * 64];   // [r][x][c], XOR-swizzled on x
    __shared__ __align__(16) ushort wL[2][64 * 64];     // [o][c],    XOR-swizzled on o
    __shared__ float biasL[64];

    const int t   = threadIdx.x;
    const int w   = t >> 6;
    const int l   = t & 63;
    const int l15 = l & 15;
    const int l4  = l >> 4;
    const int x0  = (blockIdx.x & 7) * 32;
    const int y0  = (blockIdx.x >> 3) * 4;
    const int b   = blockIdx.y;

    for (int q = t; q < 6 * 34 * 8; q += 256) {
        int r   = q / 272;
        int rem = q - r * 272;
        int x   = rem >> 3;
        int c8  = rem & 7;
        int gy = y0 - 1 + r;
        int gx = x0 - 1 + x;
        uint4 v = make_uint4(0u, 0u, 0u, 0u);
        if ((unsigned)gy < HF && (unsigned)gx < WF) {
            size_t pos = (size_t)(b * HF + gy) * WF + gx;
            if (IN_MODE == 1) {
                v = *(const uint4*)(inB + pos * 64 + c8 * 8);
            } else if (b < 2) {
                const float4* s = (const float4*)(x2 + pos * 64 + c8 * 8);
                float4 u0 = s[0], u1 = s[1];
                v = make_uint4(pack2(u0.x, u0.y), pack2(u0.z, u0.w),
                               pack2(u1.x, u1.y), pack2(u1.z, u1.w));
            } else {
                size_t p2 = (size_t)((b - 2) * HF + gy) * WF + gx;
                v = *(const uint4*)(upB + p2 * 64 + c8 * 8);
            }
        }
        int ad = (q * 16) ^ ((x & 7) << 4);
        *(uint4*)((char*)inL + ad) = v;
    }
    {
        const uint4* src = (const uint4*)wT;
        for (int q = t; q < 512; q += 256) {
            int o  = q >> 3;
            int ad = (q * 16) ^ ((o & 7) << 4);
            *(uint4*)((char*)wL[0] + ad) = src[q];
        }
    }
    if (t < 64) biasL[t] = bias[t];
    __syncthreads();

    f32x4 acc[8];
#pragma unroll
    for (int a = 0; a < 8; ++a) acc[a] = (f32x4){0.f, 0.f, 0.f, 0.f};

#pragma unroll
    for (int tap = 0; tap < 9; ++tap) {
        if (tap < 8) {
            const uint4* src = (const uint4*)(wT + (tap + 1) * 4096);
            ushort* dstw = wL[(tap + 1) & 1];
            for (int q = t; q < 512; q += 256) {
                int o  = q >> 3;
                int ad = (q * 16) ^ ((o & 7) << 4);
                *(uint4*)((char*)dstw + ad) = src[q];
            }
        }
        const int ky = tap / 3, kx = tap % 3;
        const char* wCur = (const char*)wL[tap & 1];
#pragma unroll
        for (int ks = 0; ks < 2; ++ks) {
            const int cb2 = ks * 64 + (l4 << 4);
            short8 ifr[2], wfr[4];
#pragma unroll
            for (int nf = 0; nf < 2; ++nf) {
                int xl = nf * 16 + l15 + kx;
                int ad = (((w + ky) * 34 + xl) * 128 + cb2) ^ ((xl & 7) << 4);
                ifr[nf] = *(const short8*)((const char*)inL + ad);
            }
#pragma unroll
            for (int wf = 0; wf < 4; ++wf) {
                int o  = wf * 16 + l15;
                int ad = (o * 128 + cb2) ^ ((o & 7) << 4);
                wfr[wf] = *(const short8*)(wCur + ad);
            }
#pragma unroll
            for (int wf = 0; wf < 4; ++wf)
#pragma unroll
                for (int nf = 0; nf < 2; ++nf) {
                    if (OUT_NHWC)
                        acc[wf * 2 + nf] = __builtin_amdgcn_mfma_f32_16x16x32_bf16(
                            wfr[wf], ifr[nf], acc[wf * 2 + nf], 0, 0, 0);
                    else
                        acc[wf * 2 + nf] = __builtin_amdgcn_mfma_f32_16x16x32_bf16(
                            ifr[nf], wfr[wf], acc[wf * 2 + nf], 0, 0, 0);
                }
        }
        if (tap < 8) __syncthreads();
    }

    const float al = alpha[0];
    const int y = y0 + w;
    if (OUT_NHWC) {
#pragma unroll
        for (int wf = 0; wf < 4; ++wf)
#pragma unroll
            for (int nf = 0; nf < 2; ++nf) {
                f32x4 v = acc[wf * 2 + nf];
                int cb = wf * 16 + (l4 << 2);
                uint lo = pack2(prelu(v.x + biasL[cb + 0], al), prelu(v.y + biasL[cb + 1], al));
                uint hi = pack2(prelu(v.z + biasL[cb + 2], al), prelu(v.w + biasL[cb + 3], al));
                int x = x0 + nf * 16 + l15;
                *(uint2*)(outB + ((size_t)(b * HF + y) * WF + x) * 64 + cb) = make_uint2(lo, hi);
            }
    } else {
#pragma unroll
        for (int wf = 0; wf < 4; ++wf)
#pragma unroll
            for (int mf = 0; mf < 2; ++mf) {
                f32x4 v = acc[wf * 2 + mf];
                int cout = wf * 16 + l15;
                int xb   = x0 + mf * 16 + (l4 << 2);
                float bb = biasL[cout];
                float4 st;
                st.x = prelu(v.x + bb, al);
                st.y = prelu(v.y + bb, al);
                st.z = prelu(v.z + bb, al);
                st.w = prelu(v.w + bb, al);
                *(float4*)(outF + (((size_t)b * 64 + cout) << 16) + y * WF + xb) = st;
            }
    }
}

// ---------------------------------------------------------------------------
extern "C" void kernel_launch(void* const* d_in, const int* in_sizes, int n_in,
                              void* d_out, int out_size, void* d_ws, size_t ws_size,
                              hipStream_t stream) {
    const float* x1  = (const float*)d_in[0];
    const float* x2  = (const float*)d_in[1];
    const float* wup = (const float*)d_in[2];
    const float* bup = (const float*)d_in[3];
    const float* w1  = (const float*)d_in[4];
    const float* b1  = (const float*)d_in[5];
    const float* a1  = (const float*)d_in[6];
    const float* w2  = (const float*)d_in[7];
    const float* b2  = (const float*)d_in[8];
    const float* a2  = (const float*)d_in[9];

    char* ws = (char*)d_ws;
    ushort* upB  = (ushort*)ws;                          // 16 MiB (b=2,3 NHWC bf16)
    ushort* hB   = (ushort*)(ws + (size_t)(16 << 20));   // 32 MiB (NHWC bf16)
    ushort* wT1  = (ushort*)(ws + (size_t)(48 << 20));   // 72 KiB
    ushort* wT2  = wT1 + 9 * 64 * 64;                    // 72 KiB
    ushort* wupT = wT2 + 9 * 64 * 64;                    // 64 KiB
    float* out = (float*)d_out;

    k_wprep<<<144, 256, 0, stream>>>(w1, w2, wT1, wT2);
    k_wprep_up<<<128, 256, 0, stream>>>(wup, wupT);
    k_upsample_mfma<<<dim3(256, 2), 512, 0, stream>>>(x1, wupT, bup, upB);
    k_conv<0, 1><<<dim3(512, 4), 256, 0, stream>>>(x2, upB, nullptr, wT1, b1, a1, hB, nullptr);
    k_conv<1, 0><<<dim3(512, 4), 256, 0, stream>>>(nullptr, nullptr, hB, wT2, b2, a2, nullptr, out);
}